// Round 18
// baseline (134.847 us; speedup 1.0000x reference)
//
#include <hip/hip_runtime.h>

#define NPTS 8192
#define DIM  128
#define NCLS 64
#define NT   64
#define NTILES (NT * (NT + 1) / 2)   // 2080 triangular tiles
#define CCAP 256                     // static per-class member capacity (max n ~170)
#define FEPS 1e-16f

// ws layout (float elements). Kernels init all state (no host memset).
#define WS_T     0          // 8192 floats: T_i = sum_{j!=i} exp(1-d_ij), label-blind
#define WS_CNT   8192       // 64 ints
#define WS_LOSS  8256       // 1 float
#define WS_DONE  8257       // 1 uint
#define WS_SQ    8258       // 8192 floats
#define WS_MEM2  16450      // 64*256 ints (static per-class member slots)
#define WS_G     32834      // byte 131336... need 16B align: 32836*4=131344 /16 ok
#define WS_G16A  32836      // 16B-aligned start of 1MB fp8 swizzled features

typedef float f32x4 __attribute__((ext_vector_type(4)));

__device__ inline float fast_sqrt(float x) {
    float r;
    asm("v_sqrt_f32 %0, %1" : "=v"(r) : "v"(x));
    return r;
}

// ---- node 1: class bucketing (blocks 0..63) + prep (blocks 64..1087) ----
// G layout (BYTE units, fp8 e4m3): tile t=i>>7 (16384 B) | chunk c=k>>3 (1024 B)
//                                  | m=i&127 (8 B) | k&7
__global__ void prep_bucket_kernel(const float* __restrict__ feat,
                                   const int* __restrict__ labels,
                                   float* __restrict__ sq,
                                   unsigned char* __restrict__ G,
                                   float* __restrict__ T,
                                   int* __restrict__ cnt,
                                   int* __restrict__ mem2,
                                   float* __restrict__ loss_sum,
                                   unsigned int* __restrict__ done) {
    __shared__ int llab[NPTS];          // 32 KB
    __shared__ int scan_arr[256];
    __shared__ int wsum[4];

    const int tid = threadIdx.x;
    const int w = tid >> 6, lane = tid & 63;

    if (blockIdx.x >= NCLS) {
        // ---------------- prep path ----------------
        const int kl = lane & 31;          // float4 column
        const int rloc = lane >> 5;
        int i = (blockIdx.x - NCLS) * 8 + w * 2 + rloc;
        float4 v = ((const float4*)(feat + (size_t)i * DIM))[kl];
        unsigned lo = (unsigned)__builtin_amdgcn_cvt_pk_fp8_f32(v.x, v.y, 0, false) & 0xffffu;
        unsigned hi = (unsigned)__builtin_amdgcn_cvt_pk_fp8_f32(v.z, v.w, 0, false);
        unsigned word = lo | (hi << 16);
        int t = i >> 7, m = i & 127;
        int c = kl >> 1, pos = (kl & 1) * 4;
        *(unsigned*)&G[(size_t)t * 16384 + c * 1024 + m * 8 + pos] = word;
        float s = v.x * v.x + v.y * v.y + v.z * v.z + v.w * v.w;
#pragma unroll
        for (int msk = 1; msk <= 16; msk <<= 1) s += __shfl_xor(s, msk, 64);
        if (kl == 0) sq[i] = s;
        if (tid < 8) T[(blockIdx.x - NCLS) * 8 + tid] = 0.0f;
        return;
    }

    // ---------------- bucket path: one block per class, LDS-local ----------------
    const int c = blockIdx.x;
    {
        const uint4* L4 = (const uint4*)labels;
        uint4* S4 = (uint4*)llab;
#pragma unroll
        for (int k = 0; k < 8; ++k) S4[k * 256 + tid] = L4[k * 256 + tid];
    }
    if (c == 0 && tid == 0) { loss_sum[0] = 0.0f; done[0] = 0u; }
    __syncthreads();

    // lane-consecutive chunks (bank-conflict-free)
    int cntloc = 0;
#pragma unroll
    for (int k = 0; k < 32; ++k) cntloc += (llab[tid + 256 * k] == c) ? 1 : 0;
    scan_arr[tid] = cntloc;
    __syncthreads();

    int v = scan_arr[tid];
    int incl = v;
#pragma unroll
    for (int o = 1; o < 64; o <<= 1) {
        int t1 = __shfl_up(incl, o, 64);
        if (lane >= o) incl += t1;
    }
    if (lane == 63) wsum[w] = incl;
    __syncthreads();
    int wpre = 0;
#pragma unroll
    for (int ww = 0; ww < 4; ++ww) if (ww < w) wpre += wsum[ww];
    int excl = wpre + incl - v;

    int r = excl;
#pragma unroll
    for (int k = 0; k < 32; ++k) {
        int idx = tid + 256 * k;
        if (llab[idx] == c) {
            mem2[c * CCAP + r] = idx;
            ++r;
        }
    }
    if (tid == 255) cnt[c] = excl + v;
}

// ---- node 2: triangular N^2 pass, label-blind T, minimal epilogue ----
__launch_bounds__(256, 4)
__global__ void gemm_T(const unsigned char* __restrict__ Gb,
                       const float* __restrict__ sq,
                       float* __restrict__ T) {
    int p = blockIdx.x;
    float disc = 64.5f * 64.5f - 2.0f * (float)p;
    int bt = (int)(64.5f - fast_sqrt(disc));
    if (bt < 0) bt = 0; if (bt > 63) bt = 63;
    while (bt > 0 && (bt * NT - (bt * (bt - 1)) / 2) > p) --bt;
    while (((bt + 1) * NT - ((bt + 1) * bt) / 2) <= p) ++bt;
    int jt = bt + (p - (bt * NT - (bt * (bt - 1)) / 2));

    __shared__ float sqi[128], sqj[128];

    const int tid = threadIdx.x;
    const int w = tid >> 6, lane = tid & 63;
    const int wr = w >> 1, wc = w & 1;
    const int q = lane >> 4, ml = lane & 15;
    const int ib = bt * 128, jb = jt * 128;
    const bool diag = (bt == jt);

    if (tid < 128) sqi[tid] = sq[ib + tid];
    else sqj[tid - 128] = sq[jb + tid - 128];
    __syncthreads();

    const long* A8 = (const long*)(Gb + (size_t)bt * 16384);
    const long* B8 = (const long*)(Gb + (size_t)jt * 16384);

    f32x4 acc[4][4];
#pragma unroll
    for (int a = 0; a < 4; ++a)
#pragma unroll
        for (int b = 0; b < 4; ++b) acc[a][b] = (f32x4){0.f, 0.f, 0.f, 0.f};

#pragma unroll
    for (int s = 0; s < 4; ++s) {
        long af[4], bf[4];
        int kbase = (s * 4 + q) * 128;
#pragma unroll
        for (int ii = 0; ii < 4; ++ii) af[ii] = A8[kbase + wr * 64 + ii * 16 + ml];
#pragma unroll
        for (int jj = 0; jj < 4; ++jj) bf[jj] = B8[kbase + wc * 64 + jj * 16 + ml];
#pragma unroll
        for (int ii = 0; ii < 4; ++ii)
#pragma unroll
            for (int jj = 0; jj < 4; ++jj)
                acc[ii][jj] = __builtin_amdgcn_mfma_f32_16x16x32_fp8_fp8(af[ii], bf[jj], acc[ii][jj], 0, 0, 0);
    }

    int cl[4]; float sj[4];
#pragma unroll
    for (int jj = 0; jj < 4; ++jj) {
        cl[jj] = wc * 64 + jj * 16 + ml;
        sj[jj] = sqj[cl[jj]];
    }
    float colsum[4] = {0.f, 0.f, 0.f, 0.f};

#pragma unroll
    for (int ii = 0; ii < 4; ++ii) {
        int rl = wr * 64 + ii * 16 + q * 4;
        float si4[4];
#pragma unroll
        for (int r = 0; r < 4; ++r) si4[r] = sqi[rl + r];
        float rs[4] = {0.f, 0.f, 0.f, 0.f};
#pragma unroll
        for (int jj = 0; jj < 4; ++jj)
#pragma unroll
            for (int r = 0; r < 4; ++r) {
                float d2 = fmaf(-2.0f, acc[ii][jj][r], si4[r] + sj[jj]);
                float d = fast_sqrt(fmaxf(d2, FEPS));
                float e = __expf(1.0f - d);
                if (diag && (rl + r == cl[jj])) e = 0.0f;   // exclude j==i only
                rs[r] += e;
                colsum[jj] += e;
            }
#pragma unroll
        for (int m = 1; m < 16; m <<= 1)
#pragma unroll
            for (int r = 0; r < 4; ++r) rs[r] += __shfl_xor(rs[r], m, 64);
        if (ml == 0) {
#pragma unroll
            for (int r = 0; r < 4; ++r) atomicAdd(&T[ib + rl + r], rs[r]);
        }
    }
    if (!diag) {
#pragma unroll
        for (int m = 16; m < 64; m <<= 1)
#pragma unroll
            for (int jj = 0; jj < 4; ++jj) colsum[jj] += __shfl_xor(colsum[jj], m, 64);
        if (q == 0) {
#pragma unroll
            for (int jj = 0; jj < 4; ++jj)
                atomicAdd(&T[jb + cl[jj]], colsum[jj]);
        }
    }
}

// ---- node 3: per-class self-contained loss (Gram via MFMA, two passes) ----
__global__ void pairB_kernel(const unsigned char* __restrict__ Gb,
                             const float* __restrict__ sq,
                             const float* __restrict__ T,
                             const int* __restrict__ cnt,
                             const int* __restrict__ mem2,
                             float* __restrict__ loss_sum,
                             unsigned int* __restrict__ done,
                             float* __restrict__ out) {
    __shared__ unsigned long long Af[16 * CCAP];   // frag [chunk][row], 32 KB
    __shared__ float Tl[CCAP], Pl[CCAP], Sl[CCAP], sql[CCAP];
    __shared__ float redf[4];
    __shared__ int s_tot;

    const int tid = threadIdx.x;
    const int w = tid >> 6, lane = tid & 63;
    const int wr = w >> 1, wc = w & 1;
    const int q = lane >> 4, ml = lane & 15;
    const int c = blockIdx.x;
    const int n = cnt[c];

    if (w == 0) {   // total positive-pair count = sum cnt^2
        int v = cnt[lane];
        int s2 = v * v;
#pragma unroll
        for (int o = 1; o < 64; o <<= 1) s2 += __shfl_xor(s2, o, 64);
        if (lane == 0) s_tot = s2;
    }

    // stage class rows (a = tid) : 16 chunks of 8 B each; zero-pad a >= n
    {
        int idx = (tid < n) ? mem2[c * CCAP + tid] : 0;
        const unsigned long long* src =
            (const unsigned long long*)(Gb + (size_t)(idx >> 7) * 16384 + (idx & 127) * 8);
        bool valid = (tid < n);
#pragma unroll
        for (int ch = 0; ch < 16; ++ch)
            Af[ch * CCAP + tid] = valid ? src[ch * 128] : 0ull;
        Tl[tid] = valid ? T[idx] : 0.f;
        sql[tid] = valid ? sq[idx] : 0.f;
        Pl[tid] = 0.f;
    }
    __syncthreads();

    const int nt = (n + 127) >> 7;   // 1 or 2 tiles per dim

    // ---- pass A: P_a = sum_{b != a} exp(1 - d_ab) ----
    for (int ta = 0; ta < nt; ++ta)
        for (int tb = 0; tb < nt; ++tb) {
            f32x4 acc[4][4];
#pragma unroll
            for (int a = 0; a < 4; ++a)
#pragma unroll
                for (int b = 0; b < 4; ++b) acc[a][b] = (f32x4){0.f, 0.f, 0.f, 0.f};
#pragma unroll
            for (int s = 0; s < 4; ++s) {
                long af[4], bf[4];
                int ch = s * 4 + q;
#pragma unroll
                for (int ii = 0; ii < 4; ++ii)
                    af[ii] = (long)Af[ch * CCAP + ta * 128 + wr * 64 + ii * 16 + ml];
#pragma unroll
                for (int jj = 0; jj < 4; ++jj)
                    bf[jj] = (long)Af[ch * CCAP + tb * 128 + wc * 64 + jj * 16 + ml];
#pragma unroll
                for (int ii = 0; ii < 4; ++ii)
#pragma unroll
                    for (int jj = 0; jj < 4; ++jj)
                        acc[ii][jj] = __builtin_amdgcn_mfma_f32_16x16x32_fp8_fp8(af[ii], bf[jj], acc[ii][jj], 0, 0, 0);
            }
#pragma unroll
            for (int ii = 0; ii < 4; ++ii) {
                int rl = ta * 128 + wr * 64 + ii * 16 + q * 4;
                float rs[4] = {0.f, 0.f, 0.f, 0.f};
#pragma unroll
                for (int jj = 0; jj < 4; ++jj) {
                    int b = tb * 128 + wc * 64 + jj * 16 + ml;
#pragma unroll
                    for (int r = 0; r < 4; ++r) {
                        int a = rl + r;
                        float d2 = fmaf(-2.0f, acc[ii][jj][r], sql[a] + sql[b]);
                        float d = fast_sqrt(fmaxf(d2, FEPS));
                        float e = __expf(1.0f - d);
                        if (a >= n || b >= n || a == b) e = 0.0f;
                        rs[r] += e;
                    }
                }
#pragma unroll
                for (int m = 1; m < 16; m <<= 1)
#pragma unroll
                    for (int r = 0; r < 4; ++r) rs[r] += __shfl_xor(rs[r], m, 64);
                if (ml == 0) {
#pragma unroll
                    for (int r = 0; r < 4; ++r) atomicAdd(&Pl[rl + r], rs[r]);
                }
            }
        }
    __syncthreads();
    Sl[tid] = Tl[tid] - Pl[tid];     // S_a (exact: same fp8 dots cancel)
    __syncthreads();

    // ---- pass B: loss over full n x n square (incl. diagonal, d = 1e-8) ----
    float total = 0.f;
    for (int ta = 0; ta < nt; ++ta)
        for (int tb = 0; tb < nt; ++tb) {
            f32x4 acc[4][4];
#pragma unroll
            for (int a = 0; a < 4; ++a)
#pragma unroll
                for (int b = 0; b < 4; ++b) acc[a][b] = (f32x4){0.f, 0.f, 0.f, 0.f};
#pragma unroll
            for (int s = 0; s < 4; ++s) {
                long af[4], bf[4];
                int ch = s * 4 + q;
#pragma unroll
                for (int ii = 0; ii < 4; ++ii)
                    af[ii] = (long)Af[ch * CCAP + ta * 128 + wr * 64 + ii * 16 + ml];
#pragma unroll
                for (int jj = 0; jj < 4; ++jj)
                    bf[jj] = (long)Af[ch * CCAP + tb * 128 + wc * 64 + jj * 16 + ml];
#pragma unroll
                for (int ii = 0; ii < 4; ++ii)
#pragma unroll
                    for (int jj = 0; jj < 4; ++jj)
                        acc[ii][jj] = __builtin_amdgcn_mfma_f32_16x16x32_fp8_fp8(af[ii], bf[jj], acc[ii][jj], 0, 0, 0);
            }
#pragma unroll
            for (int ii = 0; ii < 4; ++ii) {
                int rl = ta * 128 + wr * 64 + ii * 16 + q * 4;
#pragma unroll
                for (int jj = 0; jj < 4; ++jj) {
                    int b = tb * 128 + wc * 64 + jj * 16 + ml;
#pragma unroll
                    for (int r = 0; r < 4; ++r) {
                        int a = rl + r;
                        if (a < n && b < n) {
                            float d;
                            if (a == b) d = 1e-8f;
                            else {
                                float d2 = fmaf(-2.0f, acc[ii][jj][r], sql[a] + sql[b]);
                                d = fast_sqrt(fmaxf(d2, FEPS));
                            }
                            float J = __logf(Sl[a] + Sl[b]) + d;
                            float h = fmaxf(J, 0.0f);
                            total += h * h;
                        }
                    }
                }
            }
        }
#pragma unroll
    for (int off = 32; off > 0; off >>= 1) total += __shfl_down(total, off, 64);
    if (lane == 0) redf[w] = total;
    __syncthreads();
    if (tid == 0) {
        atomicAdd(loss_sum, redf[0] + redf[1] + redf[2] + redf[3]);
        __threadfence();
        unsigned int t = atomicAdd(done, 1u);
        if (t == gridDim.x - 1) {
            float tot = atomicAdd(loss_sum, 0.0f);
            out[0] = tot / (2.0f * (float)s_tot);
        }
    }
}

extern "C" void kernel_launch(void* const* d_in, const int* in_sizes, int n_in,
                              void* d_out, int out_size, void* d_ws, size_t ws_size,
                              hipStream_t stream) {
    const float* feat = (const float*)d_in[0];
    const int* labels = (const int*)d_in[1];

    float* ws = (float*)d_ws;
    float* T = ws + WS_T;
    int* cnt = (int*)(ws + WS_CNT);
    float* loss_sum = ws + WS_LOSS;
    unsigned int* done = (unsigned int*)(ws + WS_DONE);
    float* sq = ws + WS_SQ;
    int* mem2 = (int*)(ws + WS_MEM2);
    unsigned char* G8 = (unsigned char*)(ws + WS_G16A);
    float* outp = (float*)d_out;

    prep_bucket_kernel<<<NCLS + NPTS / 8, 256, 0, stream>>>(
        feat, labels, sq, G8, T, cnt, mem2, loss_sum, done);              // node 1
    gemm_T<<<NTILES, 256, 0, stream>>>(G8, sq, T);                        // node 2
    pairB_kernel<<<NCLS, 256, 0, stream>>>(G8, sq, T, cnt, mem2,
                                           loss_sum, done, outp);         // node 3
}